// Round 5
// baseline (23548.889 us; speedup 1.0000x reference)
//
#include <hip/hip_runtime.h>
#include <math.h>

namespace {

constexpr int BSZ = 256;   // batch
constexpr int SEQ = 512;   // encoder seq len
constexpr int KIN = 64;    // encoder input feature dim
constexpr int HID = 1024;  // hidden dim
constexpr int GD  = 3072;  // 3*HID
constexpr int VOC = 512;   // vocab
constexpr int TT  = 64;    // decoder steps

typedef _Float16 half_t;
typedef _Float16 half4 __attribute__((ext_vector_type(4)));
typedef _Float16 half8 __attribute__((ext_vector_type(8)));
typedef float f32x4 __attribute__((ext_vector_type(4)));

constexpr float LOSCL = 4096.f;        // lo-part scale 2^12
constexpr float LOINV = 1.f / 4096.f;

// XCD-aware decode for 256-block tile sets: 8 m-tiles (32 rows) x 32 c-tiles
// (32 cols). All m-tiles of a c-slice share blk&7 -> same XCD.
__device__ __forceinline__ void decode_mc(int bb, int& m0, int& c0) {
  int c_lo = bb & 7, rest = bb >> 3;
  int m = rest & 7, c_hi = rest >> 3;      // m in [0,8), c_hi in [0,4)
  m0 = m * 32;
  c0 = (c_hi * 8 + c_lo) * 32;
}

// ---------------------------------------------------------------------------
// Weight swizzle (one-time): rewrite W [NG*HIDR][NKCH*64] f32 into hi/lo fp16
// arrays in MFMA fragment order (layout identical to R0 — verified):
//   off = ((((ct*NKCH + kc)*4 + w4)*NG + g)*512) + l*8 + j
//   value = W[g*HIDR + ct*32 + (w4&1)*16 + (l&15)]
//            [kc*64 + (w4>>1)*32 + (l>>4)*8 + j]
// ---------------------------------------------------------------------------
__global__ __launch_bounds__(256) void swz_kernel(
    const float* __restrict__ src, half_t* __restrict__ hi,
    half_t* __restrict__ lo, int NG, int NKCH, int HIDR, int n)
{
  int i = blockIdx.x * 256 + threadIdx.x;
  if (i >= n) return;
  int j = i & 7, l = (i >> 3) & 63;
  int frag = i >> 9;
  int g = frag % NG;
  int rest = frag / NG;
  int w4 = rest & 3;
  int rest2 = rest >> 2;
  int kc = rest2 % NKCH;
  int ct = rest2 / NKCH;
  int ldw = NKCH * 64;
  int row = g * HIDR + ct * 32 + (w4 & 1) * 16 + (l & 15);
  int col = kc * 64 + (w4 >> 1) * 32 + (l >> 4) * 8 + j;
  float f = src[(size_t)row * ldw + col];
  half_t h = (half_t)f;
  hi[i] = h;
  lo[i] = (half_t)((f - (float)h) * LOSCL);
}

// x pre-split (one-time): x f32 -> xhi/xlo fp16, same linear (b,s,k) layout.
__global__ __launch_bounds__(256) void xsplit_kernel(
    const float* __restrict__ x, half_t* __restrict__ xhi,
    half_t* __restrict__ xlo, int n4)
{
  int i = blockIdx.x * 256 + threadIdx.x;
  if (i >= n4) return;
  float4 v = ((const float4*)x)[i];
  float vv[4] = {v.x, v.y, v.z, v.w};
  half4 h, lo;
  #pragma unroll
  for (int j = 0; j < 4; ++j) {
    float f = vv[j]; half_t hh = (half_t)f;
    h[j] = hh; lo[j] = (half_t)((f - (float)hh) * LOSCL);
  }
  ((half4*)xhi)[i] = h;
  ((half4*)xlo)[i] = lo;
}

// LDS A tile: [buf][split][row][134]  (+6 pad -> 268B row stride = 67 dwords
// ≡ 3 mod 32). Bank math: ds_read_b128 lanes (lr,lk) hit (3*lr+4*lk)%32 →
// ≤3-way; ds_write_b128 (arow,aseg) hit (3*arow+8*aseg)%32 → exact 2-way
// (free). The old +8 pad (68 dw ≡ 4 mod 32) was 8-way on BOTH paths
// (4*(lr+lk)%8 groups) — ~3x LDS cost per m136. 34,304 B -> 2 blocks/CU.
typedef half_t AldsT[2][2][32][134];

// ---------------------------------------------------------------------------
// Split-fp16 GEMM core, 128-K chunks, SINGLE barrier per chunk. A is
// PRE-SPLIT in global (hi/lo fp16 row-major, lda in halfs) — staging is a
// pure load->ds_write copy (no conversion VALU in the hot loop).
// Per chunk: [write A(ch)->buf(ch&1)] [barrier] [issue A/B(ch+1) loads]
// [MFMA from buf(ch&1) x B(ch)]. Safe: iter ch+2's writes to buf(ch&1) are
// separated from iter ch's reads by the barrier at iter ch+1.
// Wave map: wv = (colg=wv&1, ksg=wv>>1); wave computes 32 rows x 16 cols x
// its 64-K half of each chunk (sub-ks s2 in {0,1} -> stored fragment
// w4 = colg + 2*s2 at kc = kc0 + 2*ch + ksg). K-partial acc -> combine_ks.
// A/B register-double-buffered; nch must be EVEN.
// ---------------------------------------------------------------------------
template<int NG, int G2>
__device__ __forceinline__ void gemm_swz128(
    const half_t* __restrict__ Ahi, const half_t* __restrict__ Alo,
    size_t lda, int nch,   // K = nch*128
    const half_t* __restrict__ Whi, const half_t* __restrict__ Wlo,
    int ct, int kc0, int nkch_tot, int m0,
    f32x4 (&aH)[4][2], f32x4 (&aL)[4][2], AldsT& Alds)
{
  const int tid = threadIdx.x;
  const int wv = tid >> 6, l = tid & 63, lr = l & 15, lk = l >> 4;
  const int colg = wv & 1, ksg = wv >> 1;
  const int arow = tid >> 3, aseg = tid & 7;
  const half_t* ahp = Ahi + (size_t)(m0 + arow) * lda + aseg * 16;
  const half_t* alp = Alo + (size_t)(m0 + arow) * lda + aseg * 16;

  const size_t FR = (size_t)NG * 512;       // halfs per (kc,w4) frag group
  const size_t S2STR = 2 * FR;              // w4 += 2  (sub-ks step)
  const size_t CSTR = 8 * FR;               // kc += 2  (chunk step)
  const size_t bbase =
      (((size_t)(ct * nkch_tot + kc0 + ksg)) * 4 + colg) * FR + l * 8;
  const half_t* bph = Whi + bbase;
  const half_t* bpl = Wlo + bbase;

  half8 paE[4], paO[4];                     // {hi seg0, hi seg1, lo seg0, lo seg1}
  half8 bhE[2 * NG], blE[2 * NG], bhO[2 * NG], blO[2 * NG];
  paE[0] = *(const half8*)(ahp);
  paE[1] = *(const half8*)(ahp + 8);
  paE[2] = *(const half8*)(alp);
  paE[3] = *(const half8*)(alp + 8);
  #pragma unroll
  for (int s2 = 0; s2 < 2; ++s2)
    #pragma unroll
    for (int g = 0; g < NG; ++g) {
      bhE[s2 * NG + g] = *(const half8*)(bph + s2 * S2STR + g * 512);
      blE[s2 * NG + g] = *(const half8*)(bpl + s2 * S2STR + g * 512);
    }

#define SWC(pac, bhc, blc, pan, bhn, bln, CH, BUF)                            \
  {                                                                           \
    *(half8*)&Alds[BUF][0][arow][aseg * 16] = pac[0];                         \
    *(half8*)&Alds[BUF][0][arow][aseg * 16 + 8] = pac[1];                     \
    *(half8*)&Alds[BUF][1][arow][aseg * 16] = pac[2];                         \
    *(half8*)&Alds[BUF][1][arow][aseg * 16 + 8] = pac[3];                     \
    __syncthreads();                                                          \
    if ((CH) + 1 < nch) {                                                     \
      const size_t aco = (size_t)((CH) + 1) * 128;                            \
      pan[0] = *(const half8*)(ahp + aco);                                    \
      pan[1] = *(const half8*)(ahp + aco + 8);                                \
      pan[2] = *(const half8*)(alp + aco);                                    \
      pan[3] = *(const half8*)(alp + aco + 8);                                \
      _Pragma("unroll") for (int s2 = 0; s2 < 2; ++s2)                        \
        _Pragma("unroll") for (int g = 0; g < NG; ++g) {                      \
          bhn[s2 * NG + g] =                                                  \
              *(const half8*)(bph + ((CH) + 1) * CSTR + s2 * S2STR + g * 512);\
          bln[s2 * NG + g] =                                                  \
              *(const half8*)(bpl + ((CH) + 1) * CSTR + s2 * S2STR + g * 512);\
        }                                                                     \
    }                                                                         \
    _Pragma("unroll") for (int s2 = 0; s2 < 2; ++s2) {                        \
      half8 ah0 = *(const half8*)&Alds[BUF][0][lr][ksg * 64 + s2 * 32 + lk * 8];      \
      half8 ah1 = *(const half8*)&Alds[BUF][0][16 + lr][ksg * 64 + s2 * 32 + lk * 8]; \
      half8 al0 = *(const half8*)&Alds[BUF][1][lr][ksg * 64 + s2 * 32 + lk * 8];      \
      half8 al1 = *(const half8*)&Alds[BUF][1][16 + lr][ksg * 64 + s2 * 32 + lk * 8]; \
      _Pragma("unroll") for (int g = 0; g < NG; ++g) {                        \
        const int slot = (g == 2) ? G2 : g;                                   \
        half8 bh = bhc[s2 * NG + g];                                          \
        half8 bl = blc[s2 * NG + g];                                          \
        aH[slot][0] = __builtin_amdgcn_mfma_f32_16x16x32_f16(ah0, bh, aH[slot][0], 0, 0, 0); \
        aH[slot][1] = __builtin_amdgcn_mfma_f32_16x16x32_f16(ah1, bh, aH[slot][1], 0, 0, 0); \
        aL[slot][0] = __builtin_amdgcn_mfma_f32_16x16x32_f16(ah0, bl, aL[slot][0], 0, 0, 0); \
        aL[slot][0] = __builtin_amdgcn_mfma_f32_16x16x32_f16(al0, bh, aL[slot][0], 0, 0, 0); \
        aL[slot][1] = __builtin_amdgcn_mfma_f32_16x16x32_f16(ah1, bl, aL[slot][1], 0, 0, 0); \
        aL[slot][1] = __builtin_amdgcn_mfma_f32_16x16x32_f16(al1, bh, aL[slot][1], 0, 0, 0); \
      }                                                                       \
    }                                                                         \
  }

  for (int ch = 0; ch < nch; ch += 2) {
    SWC(paE, bhE, blE, paO, bhO, blO, ch, 0)
    SWC(paO, bhO, blO, paE, bhE, blE, (ch + 1), 1)
  }
#undef SWC
}

// K=64 pass (encoder layer0 ih). Single chunk into buf0; wave (colg,ksg)
// takes stored fragment w4 = colg + 2*ksg (its 32-K half).
// A pre-split; staging is pure copy. Safe to write buf0 immediately after an
// even-nch gemm_swz128 pass.
template<int NG, int G2>
__device__ __forceinline__ void gemm_swz64(
    const half_t* __restrict__ Ahi, const half_t* __restrict__ Alo,
    size_t lda,
    const half_t* __restrict__ Whi, const half_t* __restrict__ Wlo,
    int ct, int nkch_tot, int m0,
    f32x4 (&aH)[4][2], f32x4 (&aL)[4][2], AldsT& Alds)
{
  const int tid = threadIdx.x;
  const int wv = tid >> 6, l = tid & 63, lr = l & 15, lk = l >> 4;
  const int colg = wv & 1, ksg = wv >> 1;
  const int arow = tid >> 3, aseg = tid & 7;
  const half_t* ahp = Ahi + (size_t)(m0 + arow) * lda + aseg * 8;
  const half_t* alp = Alo + (size_t)(m0 + arow) * lda + aseg * 8;

  const size_t FR = (size_t)NG * 512;
  const size_t bbase =
      (((size_t)(ct * nkch_tot)) * 4 + (colg + 2 * ksg)) * FR + l * 8;
  half8 bh[NG], bl[NG];
  #pragma unroll
  for (int g = 0; g < NG; ++g) {
    bh[g] = *(const half8*)(Whi + bbase + g * 512);
    bl[g] = *(const half8*)(Wlo + bbase + g * 512);
  }
  half8 hi8 = *(const half8*)(ahp);
  half8 lo8 = *(const half8*)(alp);
  *(half8*)&Alds[0][0][arow][aseg * 8] = hi8;
  *(half8*)&Alds[0][1][arow][aseg * 8] = lo8;
  __syncthreads();
  half8 ah0 = *(const half8*)&Alds[0][0][lr][ksg * 32 + lk * 8];
  half8 ah1 = *(const half8*)&Alds[0][0][16 + lr][ksg * 32 + lk * 8];
  half8 al0 = *(const half8*)&Alds[0][1][lr][ksg * 32 + lk * 8];
  half8 al1 = *(const half8*)&Alds[0][1][16 + lr][ksg * 32 + lk * 8];
  #pragma unroll
  for (int g = 0; g < NG; ++g) {
    const int slot = (g == 2) ? G2 : g;
    aH[slot][0] = __builtin_amdgcn_mfma_f32_16x16x32_f16(ah0, bh[g], aH[slot][0], 0, 0, 0);
    aH[slot][1] = __builtin_amdgcn_mfma_f32_16x16x32_f16(ah1, bh[g], aH[slot][1], 0, 0, 0);
    aL[slot][0] = __builtin_amdgcn_mfma_f32_16x16x32_f16(ah0, bl[g], aL[slot][0], 0, 0, 0);
    aL[slot][0] = __builtin_amdgcn_mfma_f32_16x16x32_f16(al0, bh[g], aL[slot][0], 0, 0, 0);
    aL[slot][1] = __builtin_amdgcn_mfma_f32_16x16x32_f16(ah1, bl[g], aL[slot][1], 0, 0, 0);
    aL[slot][1] = __builtin_amdgcn_mfma_f32_16x16x32_f16(al1, bh[g], aL[slot][1], 0, 0, 0);
  }
}

// Fold lo into hi, then fold ksg=1 partials into ksg=0 waves via LDS
// exchange. Lane stride = NS*8+1 dwords (odd -> 2-way banks; the old NS*8
// stride was ≡0 mod 32 = whole-wave same-bank). Scalar f32 ops (odd stride
// breaks 16B alignment for vector ops). xch >= 128*(NS*8+1) floats; A-LDS
// region reused — the leading __syncthreads makes that safe. tid<128 then
// holds finals. Callers touching LDS after this must __syncthreads() first.
template<int NS>
__device__ __forceinline__ void combine_ks(
    f32x4 (&aH)[4][2], f32x4 (&aL)[4][2], float* __restrict__ xch)
{
  const int tid = threadIdx.x;
  const int wv = tid >> 6, l = tid & 63;
  const int colg = wv & 1, ksg = wv >> 1;
  #pragma unroll
  for (int q = 0; q < NS; ++q)
    #pragma unroll
    for (int mf = 0; mf < 2; ++mf)
      aH[q][mf] = aH[q][mf] + aL[q][mf] * LOINV;
  __syncthreads();                        // last gemm LDS reads complete
  float* base = xch + ((size_t)colg * 64 + l) * (NS * 8 + 1);
  if (ksg == 1) {
    #pragma unroll
    for (int q = 0; q < NS; ++q)
      #pragma unroll
      for (int mf = 0; mf < 2; ++mf)
        #pragma unroll
        for (int i = 0; i < 4; ++i)
          base[q * 8 + mf * 4 + i] = aH[q][mf][i];
  }
  __syncthreads();
  if (ksg == 0) {
    #pragma unroll
    for (int q = 0; q < NS; ++q)
      #pragma unroll
      for (int mf = 0; mf < 2; ++mf)
        #pragma unroll
        for (int i = 0; i < 4; ++i)
          aH[q][mf][i] = aH[q][mf][i] + base[q * 8 + mf * 4 + i];
  }
}

// GRU epilogue (runs on tid<128 after combine_ks). vv = folded slots.
// Writes f32 h AND pre-split hi/lo fp16 h (consumed as GEMM-A next step).
__device__ __forceinline__ void gru_epi32s(
    f32x4 (&vv)[4][2],
    const float* __restrict__ bih, const float* __restrict__ bhh,
    const float* __restrict__ hprev, float* __restrict__ hout,
    half_t* __restrict__ houthi, half_t* __restrict__ houtlo,
    int m0, int c0)
{
  const int tid = threadIdx.x;
  if (tid >= 128) return;
  const int wv = tid >> 6, l = tid & 63, lr = l & 15, lk = l >> 4;
  const int c = c0 + (wv & 1) * 16 + lr;
  float bhr = bhh[c], bhz = bhh[HID + c], bhn = bhh[2 * HID + c];
  float bir = 0.f, biz = 0.f, bin = 0.f;
  if (bih) { bir = bih[c]; biz = bih[HID + c]; bin = bih[2 * HID + c]; }
  #pragma unroll
  for (int mf = 0; mf < 2; ++mf) {
    #pragma unroll
    for (int i = 0; i < 4; ++i) {
      int b = m0 + mf * 16 + lk * 4 + i;
      float rs = vv[0][mf][i] + bhr + bir;
      float zs = vv[1][mf][i] + bhz + biz;
      float nx = vv[2][mf][i] + bin;
      float nh = vv[3][mf][i] + bhn;
      float r = 1.f / (1.f + expf(-rs));
      float z = 1.f / (1.f + expf(-zs));
      float n = tanhf(nx + r * nh);
      float o = (1.f - z) * n + z * hprev[(size_t)b * HID + c];
      hout[(size_t)b * HID + c] = o;
      half_t hv = (half_t)o;
      houthi[(size_t)b * HID + c] = hv;
      houtlo[(size_t)b * HID + c] = (half_t)((o - (float)hv) * LOSCL);
    }
  }
}

// Write 3 gate slots (0,1,s2) as f32 partials P[3][BSZ][HID]. tid<128.
__device__ __forceinline__ void write_partials32(
    f32x4 (&vv)[4][2], int s2, float* __restrict__ P, int m0, int c0)
{
  const int tid = threadIdx.x;
  if (tid >= 128) return;
  const int wv = tid >> 6, l = tid & 63, lr = l & 15, lk = l >> 4;
  const int c = c0 + (wv & 1) * 16 + lr;
  #pragma unroll
  for (int g = 0; g < 3; ++g) {
    const int slot = (g == 2) ? s2 : g;
    #pragma unroll
    for (int mf = 0; mf < 2; ++mf) {
      #pragma unroll
      for (int i = 0; i < 4; ++i) {
        int b = m0 + mf * 16 + lk * 4 + i;
        P[((size_t)g * BSZ + b) * HID + c] = vv[slot][mf][i];
      }
    }
  }
}

#define INIT_ACC(aH, aL)                                  \
  _Pragma("unroll") for (int q = 0; q < 4; ++q)           \
    _Pragma("unroll") for (int m_ = 0; m_ < 2; ++m_) {    \
      aH[q][m_] = (f32x4){0.f, 0.f, 0.f, 0.f};            \
      aL[q][m_] = (f32x4){0.f, 0.f, 0.f, 0.f};            \
    }

// ---------------------------------------------------------------------------
// Encoder step: blocks [0,256) layer0 @ s; [256,512) layer1 @ s-1 (pipelined).
// Ring: layer writes slot (s&1), reads slot ((s+1)&1). 2 blocks/CU.
// ---------------------------------------------------------------------------
__global__ __launch_bounds__(256, 2) void enc_step_mfma(
    int s, const half_t* __restrict__ xhi, const half_t* __restrict__ xlo,
    const half_t* __restrict__ Wih0h, const half_t* __restrict__ Wih0l,
    const float* __restrict__ bih0,
    const half_t* __restrict__ Whh0h, const half_t* __restrict__ Whh0l,
    const float* __restrict__ bhh0,
    const half_t* __restrict__ Wih1h, const half_t* __restrict__ Wih1l,
    const float* __restrict__ bih1,
    const half_t* __restrict__ Whh1h, const half_t* __restrict__ Whh1l,
    const float* __restrict__ bhh1,
    float* __restrict__ h0f, float* __restrict__ h1f,
    half_t* __restrict__ h0hi, half_t* __restrict__ h0lo,
    half_t* __restrict__ h1hi, half_t* __restrict__ h1lo)
{
  __shared__ __align__(16) AldsT Alds;
  f32x4 aH[4][2], aL[4][2];
  INIT_ACC(aH, aL)
  const size_t BH = (size_t)BSZ * HID;
  int blk = blockIdx.x;
  if (blk < 256) {
    if (s >= SEQ) return;
    int m0, c0; decode_mc(blk, m0, c0);
    int ct = c0 >> 5;
    const size_t sp = ((s + 1) & 1) * BH, so = (s & 1) * BH;
    gemm_swz128<3, 3>(h0hi + sp, h0lo + sp, HID, 8, Whh0h, Whh0l,
                      ct, 0, 16, m0, aH, aL, Alds);
    gemm_swz64<3, 2>(xhi + (size_t)s * KIN, xlo + (size_t)s * KIN,
                     (size_t)SEQ * KIN, Wih0h, Wih0l, ct, 1, m0, aH, aL, Alds);
    combine_ks<4>(aH, aL, (float*)Alds);
    gru_epi32s(aH, bih0, bhh0, h0f + sp, h0f + so, h0hi + so, h0lo + so,
               m0, c0);
  } else {
    if (s < 1) return;
    int u = s - 1;
    int m0, c0; decode_mc(blk - 256, m0, c0);
    int ct = c0 >> 5;
    const size_t up = ((u + 1) & 1) * BH, uo = (u & 1) * BH;
    gemm_swz128<3, 3>(h1hi + up, h1lo + up, HID, 8, Whh1h, Whh1l,
                      ct, 0, 16, m0, aH, aL, Alds);
    gemm_swz128<3, 2>(h0hi + uo, h0lo + uo, HID, 8, Wih1h, Wih1l,
                      ct, 0, 16, m0, aH, aL, Alds);
    combine_ks<4>(aH, aL, (float*)Alds);
    gru_epi32s(aH, bih1, bhh1, h1f + up, h1f + uo, h1hi + uo, h1lo + uo,
               m0, c0);
  }
}

// Decoder layer0 main: hh GEMM, K-split x2 -> 512 blocks (2/CU TLP).
// Pg layout: [kh][3][BSZ][HID].
__global__ __launch_bounds__(256, 2) void gru0_main(
    const half_t* __restrict__ hphi, const half_t* __restrict__ hplo,
    const half_t* __restrict__ Whhh, const half_t* __restrict__ Whhl,
    float* __restrict__ Pg)
{
  __shared__ __align__(16) AldsT Alds;
  f32x4 aH[4][2], aL[4][2];
  INIT_ACC(aH, aL)
  int bb = blockIdx.x;
  int kh = bb >> 8;
  int m0, c0; decode_mc(bb & 255, m0, c0);
  int ct = c0 >> 5;
  gemm_swz128<3, 3>(hphi + kh * 512, hplo + kh * 512, HID, 4, Whhh, Whhl,
                    ct, kh * 8, 16, m0, aH, aL, Alds);
  combine_ks<4>(aH, aL, (float*)Alds);
  write_partials32(aH, 3, Pg + (size_t)kh * 3 * BSZ * HID, m0, c0);
}

// Decoder layer0 epilogue: combine K-halves + E-gather (token from tok[]) +
// GRU cell. bih0 folded into E. Also writes pre-split hi/lo h.
__global__ __launch_bounds__(256) void gru0_epi(
    const float* __restrict__ Pg, const float* __restrict__ bhh,
    const float* __restrict__ E, const int* __restrict__ tok,
    const float* __restrict__ hprev, float* __restrict__ hout,
    half_t* __restrict__ houthi, half_t* __restrict__ houtlo)
{
  int idx = (blockIdx.x * 256 + threadIdx.x) * 4;
  int b = idx >> 10, c = idx & 1023;
  const size_t BH3 = (size_t)3 * BSZ * HID;
  float4 r0 = *(const float4*)&Pg[((size_t)0 * BSZ + b) * HID + c];
  float4 z0 = *(const float4*)&Pg[((size_t)1 * BSZ + b) * HID + c];
  float4 n0 = *(const float4*)&Pg[((size_t)2 * BSZ + b) * HID + c];
  float4 r1 = *(const float4*)&Pg[BH3 + ((size_t)0 * BSZ + b) * HID + c];
  float4 z1 = *(const float4*)&Pg[BH3 + ((size_t)1 * BSZ + b) * HID + c];
  float4 n1 = *(const float4*)&Pg[BH3 + ((size_t)2 * BSZ + b) * HID + c];
  const float* Er = E + (size_t)tok[b] * GD;
  float4 exr = *(const float4*)&Er[c];
  float4 exz = *(const float4*)&Er[HID + c];
  float4 exn = *(const float4*)&Er[2 * HID + c];
  float4 hp = *(const float4*)&hprev[(size_t)b * HID + c];
  float r0v[4] = {r0.x, r0.y, r0.z, r0.w}, z0v[4] = {z0.x, z0.y, z0.z, z0.w};
  float n0v[4] = {n0.x, n0.y, n0.z, n0.w}, r1v[4] = {r1.x, r1.y, r1.z, r1.w};
  float z1v[4] = {z1.x, z1.y, z1.z, z1.w}, n1v[4] = {n1.x, n1.y, n1.z, n1.w};
  float exrv[4] = {exr.x, exr.y, exr.z, exr.w};
  float exzv[4] = {exz.x, exz.y, exz.z, exz.w};
  float exnv[4] = {exn.x, exn.y, exn.z, exn.w};
  float hpv[4] = {hp.x, hp.y, hp.z, hp.w};
  float ov[4];
  half4 hh, hl;
  #pragma unroll
  for (int j = 0; j < 4; ++j) {
    int cc = c + j;
    float rs = r0v[j] + r1v[j] + bhh[cc] + exrv[j];
    float zs = z0v[j] + z1v[j] + bhh[HID + cc] + exzv[j];
    float nh = n0v[j] + n1v[j] + bhh[2 * HID + cc];
    float r = 1.f / (1.f + expf(-rs));
    float z = 1.f / (1.f + expf(-zs));
    float n = tanhf(exnv[j] + r * nh);
    ov[j] = (1.f - z) * n + z * hpv[j];
    half_t hv = (half_t)ov[j];
    hh[j] = hv;
    hl[j] = (half_t)((ov[j] - (float)hv) * LOSCL);
  }
  float4 o; o.x = ov[0]; o.y = ov[1]; o.z = ov[2]; o.w = ov[3];
  *(float4*)&hout[(size_t)b * HID + c] = o;
  *(half4*)&houthi[(size_t)b * HID + c] = hh;
  *(half4*)&houtlo[(size_t)b * HID + c] = hl;
}

// Decoder layer1: hh and ih passes as parallel blocks writing partials.
// grid 512: [0,256) hh (A = hd1prev splits), [256,512) ih (A = ho0 splits).
__global__ __launch_bounds__(256, 2) void dec_l1_main(
    const half_t* __restrict__ hd1hi, const half_t* __restrict__ hd1lo,
    const half_t* __restrict__ ho0hi, const half_t* __restrict__ ho0lo,
    const half_t* __restrict__ Whhh, const half_t* __restrict__ Whhl,
    const half_t* __restrict__ Wihh, const half_t* __restrict__ Wihl,
    float* __restrict__ Phh, float* __restrict__ Pih)
{
  __shared__ __align__(16) AldsT Alds;
  f32x4 aH[4][2], aL[4][2];
  INIT_ACC(aH, aL)
  int bb = blockIdx.x;
  if (bb < 256) {
    int m0, c0; decode_mc(bb, m0, c0);
    gemm_swz128<3, 3>(hd1hi, hd1lo, HID, 8, Whhh, Whhl, c0 >> 5, 0, 16, m0,
                      aH, aL, Alds);
    combine_ks<4>(aH, aL, (float*)Alds);
    write_partials32(aH, 3, Phh, m0, c0);
  } else {
    int m0, c0; decode_mc(bb - 256, m0, c0);
    gemm_swz128<3, 2>(ho0hi, ho0lo, HID, 8, Wihh, Wihl, c0 >> 5, 0, 16, m0,
                      aH, aL, Alds);
    combine_ks<4>(aH, aL, (float*)Alds);
    write_partials32(aH, 2, Pih, m0, c0);
  }
}

// Decoder layer1 epilogue: combine partials -> GRU cell (+ split h out).
__global__ __launch_bounds__(256) void dec_l1_epi(
    const float* __restrict__ Phh, const float* __restrict__ Pih,
    const float* __restrict__ bih, const float* __restrict__ bhh,
    const float* __restrict__ hprev, float* __restrict__ hout,
    half_t* __restrict__ houthi, half_t* __restrict__ houtlo)
{
  int idx = (blockIdx.x * 256 + threadIdx.x) * 4;
  int b = idx >> 10, c = idx & 1023;
  float4 rh = *(const float4*)&Phh[((size_t)0 * BSZ + b) * HID + c];
  float4 zh = *(const float4*)&Phh[((size_t)1 * BSZ + b) * HID + c];
  float4 nh = *(const float4*)&Phh[((size_t)2 * BSZ + b) * HID + c];
  float4 rx = *(const float4*)&Pih[((size_t)0 * BSZ + b) * HID + c];
  float4 zx = *(const float4*)&Pih[((size_t)1 * BSZ + b) * HID + c];
  float4 nx = *(const float4*)&Pih[((size_t)2 * BSZ + b) * HID + c];
  float4 hp = *(const float4*)&hprev[(size_t)b * HID + c];
  float rhv[4] = {rh.x, rh.y, rh.z, rh.w}, zhv[4] = {zh.x, zh.y, zh.z, zh.w};
  float nhv[4] = {nh.x, nh.y, nh.z, nh.w}, rxv[4] = {rx.x, rx.y, rx.z, rx.w};
  float zxv[4] = {zx.x, zx.y, zx.z, zx.w}, nxv[4] = {nx.x, nx.y, nx.z, nx.w};
  float hpv[4] = {hp.x, hp.y, hp.z, hp.w};
  float ov[4];
  half4 hh, hl;
  #pragma unroll
  for (int j = 0; j < 4; ++j) {
    int cc = c + j;
    float r = 1.f / (1.f + expf(-(rhv[j] + rxv[j] + bhh[cc] + bih[cc])));
    float z = 1.f / (1.f + expf(-(zhv[j] + zxv[j] + bhh[HID + cc] + bih[HID + cc])));
    float n = tanhf(nxv[j] + bih[2 * HID + cc] + r * (nhv[j] + bhh[2 * HID + cc]));
    ov[j] = (1.f - z) * n + z * hpv[j];
    half_t hv = (half_t)ov[j];
    hh[j] = hv;
    hl[j] = (half_t)((ov[j] - (float)hv) * LOSCL);
  }
  float4 o; o.x = ov[0]; o.y = ov[1]; o.z = ov[2]; o.w = ov[3];
  *(float4*)&hout[(size_t)b * HID + c] = o;
  *(half4*)&houthi[(size_t)b * HID + c] = hh;
  *(half4*)&houtlo[(size_t)b * HID + c] = hl;
}

// FC main: K-split x2 partial logits (no bias). grid 256 = 2kh x 8m x 16v.
// Pfc layout: [kh][BSZ][VOC]. A = ho1 splits.
__global__ __launch_bounds__(256, 2) void fc_main(
    const half_t* __restrict__ hhi, const half_t* __restrict__ hlo,
    const half_t* __restrict__ Wh, const half_t* __restrict__ Wl,
    float* __restrict__ Pfc)
{
  __shared__ __align__(16) AldsT Alds;
  f32x4 aH[4][2], aL[4][2];
  INIT_ACC(aH, aL)
  int bb = blockIdx.x;
  int kh = bb >> 7, sub = bb & 127;
  int v_lo = sub & 7, rest = sub >> 3;
  int m = rest & 7, v_hi = rest >> 3;      // m in [0,8), v_hi in [0,2)
  int m0 = m * 32, v0 = (v_hi * 8 + v_lo) * 32;
  gemm_swz128<1, 0>(hhi + kh * 512, hlo + kh * 512, HID, 4, Wh, Wl,
                    v0 >> 5, kh * 8, 16, m0, aH, aL, Alds);
  combine_ks<1>(aH, aL, (float*)Alds);

  const int tid = threadIdx.x;
  if (tid >= 128) return;
  const int wv = tid >> 6, l = tid & 63, lr = l & 15, lk = l >> 4;
  int v = v0 + (wv & 1) * 16 + lr;
  float* P = Pfc + (size_t)kh * BSZ * VOC;
  #pragma unroll
  for (int mf = 0; mf < 2; ++mf) {
    #pragma unroll
    for (int i = 0; i < 4; ++i) {
      int b = m0 + mf * 16 + lk * 4 + i;
      P[(size_t)b * VOC + v] = aH[0][mf][i];
    }
  }
}

// FC epilogue: sum partials + bias, write logits, row-argmax -> tok.
// grid 256 (one row per block). First-max tie-break == jnp.argmax.
__global__ __launch_bounds__(256) void fc_epi(
    const float* __restrict__ Pfc, const float* __restrict__ fcb,
    float* __restrict__ out, int t, int* __restrict__ tok)
{
  __shared__ float sv[4];
  __shared__ int si[4];
  int b = blockIdx.x, tid = threadIdx.x;
  int va = tid, vb = tid + 256;
  float lga = Pfc[(size_t)b * VOC + va] + Pfc[((size_t)BSZ + b) * VOC + va] + fcb[va];
  float lgb = Pfc[(size_t)b * VOC + vb] + Pfc[((size_t)BSZ + b) * VOC + vb] + fcb[vb];
  out[((size_t)b * TT + t) * VOC + va] = lga;
  out[((size_t)b * TT + t) * VOC + vb] = lgb;
  float best = lga; int bi = va;
  if (lgb > best) { best = lgb; bi = vb; }   // va < vb: tie keeps va
  #pragma unroll
  for (int off = 1; off < 64; off <<= 1) {
    float ov = __shfl_xor(best, off);
    int oi = __shfl_xor(bi, off);
    if (ov > best || (ov == best && oi < bi)) { best = ov; bi = oi; }
  }
  int wv = tid >> 6;
  if ((tid & 63) == 0) { sv[wv] = best; si[wv] = bi; }
  __syncthreads();
  if (tid == 0) {
    #pragma unroll
    for (int w = 1; w < 4; ++w)
      if (sv[w] > best || (sv[w] == best && si[w] < bi)) { best = sv[w]; bi = si[w]; }
    tok[b] = bi;
  }
}

// E0[v][g] = emb[v] @ dec_Wih0[g] + dec_bih0[g]  (f32 VALU, one-time)
__global__ __launch_bounds__(256) void e0_kernel(
    const float* __restrict__ emb, const float* __restrict__ Wih,
    const float* __restrict__ bih, float* __restrict__ E0)
{
  __shared__ float As[32][34];
  __shared__ float Bs[32][68];
  int m0 = (blockIdx.x & 15) << 5;
  int c0 = (blockIdx.x >> 4) << 6;
  int tid = threadIdx.x, tx = tid & 15, ty = tid >> 4;
  float acc[2][4] = {};
  for (int k0 = 0; k0 < HID; k0 += 32) {
    { int m = tid >> 3, kq = (tid & 7) << 2;
      float4 v = *(const float4*)(emb + (size_t)(m0 + m) * HID + k0 + kq);
      As[kq+0][m] = v.x; As[kq+1][m] = v.y; As[kq+2][m] = v.z; As[kq+3][m] = v.w; }
    #pragma unroll
    for (int r = 0; r < 2; ++r) {
      int idx = (r << 8) + tid;
      int n = idx >> 3, kq = (idx & 7) << 2;
      float4 v = *(const float4*)(Wih + (size_t)(c0 + n) * HID + k0 + kq);
      Bs[kq+0][n] = v.x; Bs[kq+1][n] = v.y; Bs[kq+2][n] = v.z; Bs[kq+3][n] = v.w;
    }
    __syncthreads();
    #pragma unroll 4
    for (int k = 0; k < 32; ++k) {
      float a0 = As[k][(ty << 1)], a1 = As[k][(ty << 1) + 1];
      float4 b = *(const float4*)&Bs[k][tx << 2];
      float bb[4] = {b.x, b.y, b.z, b.w};
      #pragma unroll
      for (int j = 0; j < 4; ++j) {
        acc[0][j] = fmaf(a0, bb[j], acc[0][j]);
        acc[1][j] = fmaf(a1, bb[j], acc[1][j]);
      }
    }
    __syncthreads();
  }
  #pragma unroll
  for (int i = 0; i < 2; ++i) {
    int v = m0 + (ty << 1) + i;
    #pragma unroll
    for (int j = 0; j < 4; ++j) {
      int g = c0 + (tx << 2) + j;
      E0[(size_t)v * GD + g] = acc[i][j] + bih[g];
    }
  }
}

} // anonymous namespace

extern "C" void kernel_launch(void* const* d_in, const int* in_sizes, int n_in,
                              void* d_out, int out_size, void* d_ws, size_t ws_size,
                              hipStream_t stream)
{
  const float* x     = (const float*)d_in[0];
  const float* emb   = (const float*)d_in[1];
  const float* eWih0 = (const float*)d_in[2];
  const float* eWhh0 = (const float*)d_in[3];
  const float* ebih0 = (const float*)d_in[4];
  const float* ebhh0 = (const float*)d_in[5];
  const float* eWih1 = (const float*)d_in[6];
  const float* eWhh1 = (const float*)d_in[7];
  const float* ebih1 = (const float*)d_in[8];
  const float* ebhh1 = (const float*)d_in[9];
  const float* dWih  = (const float*)d_in[10];
  const float* dWhh  = (const float*)d_in[11];
  const float* dbih  = (const float*)d_in[12];
  const float* dbhh  = (const float*)d_in[13];
  const float* fcW   = (const float*)d_in[14];
  const float* fcb   = (const float*)d_in[15];
  float* out = (float*)d_out;

  const size_t BH = (size_t)BSZ * HID;
  const size_t XN = (size_t)BSZ * SEQ * KIN;

  // ---- ws bump allocator ----
  char* p = (char*)d_ws;
  auto alloc = [&](size_t bytes) {
    char* r = p; p += (bytes + 255) & ~(size_t)255; return r;
  };
  float* E0   = (float*)alloc((size_t)VOC * GD * 4);
  float* h0f  = (float*)alloc(2 * BH * 4);
  float* h1f  = (float*)alloc(2 * BH * 4);
  float* hd0f = (float*)alloc(2 * BH * 4);
  float* hd1f = (float*)alloc(2 * BH * 4);
  float* Phh  = (float*)alloc(3 * BH * 4);
  float* Pih  = (float*)alloc(3 * BH * 4);
  float* Pg   = (float*)alloc(6 * BH * 4);           // gru0 K-split partials
  float* Pfc  = (float*)alloc((size_t)2 * BSZ * VOC * 4);
  const int NW_IH0 = GD * KIN, NW = GD * HID, NW_FC = VOC * HID;
  half_t* eWih0h = (half_t*)alloc((size_t)NW_IH0 * 2);
  half_t* eWih0l = (half_t*)alloc((size_t)NW_IH0 * 2);
  half_t* eWhh0h = (half_t*)alloc((size_t)NW * 2);
  half_t* eWhh0l = (half_t*)alloc((size_t)NW * 2);
  half_t* eWih1h = (half_t*)alloc((size_t)NW * 2);
  half_t* eWih1l = (half_t*)alloc((size_t)NW * 2);
  half_t* eWhh1h = (half_t*)alloc((size_t)NW * 2);
  half_t* eWhh1l = (half_t*)alloc((size_t)NW * 2);
  half_t* dWhh0h = (half_t*)alloc((size_t)NW * 2);
  half_t* dWhh0l = (half_t*)alloc((size_t)NW * 2);
  half_t* dWhh1h = (half_t*)alloc((size_t)NW * 2);
  half_t* dWhh1l = (half_t*)alloc((size_t)NW * 2);
  half_t* dWih1h = (half_t*)alloc((size_t)NW * 2);
  half_t* dWih1l = (half_t*)alloc((size_t)NW * 2);
  half_t* fcWh   = (half_t*)alloc((size_t)NW_FC * 2);
  half_t* fcWl   = (half_t*)alloc((size_t)NW_FC * 2);
  // pre-split A arrays (hi/lo fp16): x one-time, h rings per-step
  half_t* xhi  = (half_t*)alloc(XN * 2);
  half_t* xlo  = (half_t*)alloc(XN * 2);
  half_t* h0hi = (half_t*)alloc(2 * BH * 2);
  half_t* h0lo = (half_t*)alloc(2 * BH * 2);
  half_t* h1hi = (half_t*)alloc(2 * BH * 2);
  half_t* h1lo = (half_t*)alloc(2 * BH * 2);
  half_t* d0hi = (half_t*)alloc(2 * BH * 2);
  half_t* d0lo = (half_t*)alloc(2 * BH * 2);
  half_t* d1hi = (half_t*)alloc(2 * BH * 2);
  half_t* d1lo = (half_t*)alloc(2 * BH * 2);
  int* tok = (int*)alloc(BSZ * 4);

  // ---- per-call init ----
  hipMemsetAsync(h0f + BH, 0, BH * 4, stream);   // h0[-1] = 0
  hipMemsetAsync(h1f + BH, 0, BH * 4, stream);   // h1[-1] = 0
  hipMemsetAsync(h0hi + BH, 0, BH * 2, stream);
  hipMemsetAsync(h0lo + BH, 0, BH * 2, stream);
  hipMemsetAsync(h1hi + BH, 0, BH * 2, stream);
  hipMemsetAsync(h1lo + BH, 0, BH * 2, stream);
  hipMemsetAsync(tok, 0, BSZ * 4, stream);       // start token 0

  // ---- one-time weight swizzles (hi/lo fp16, MFMA fragment order) ----
  swz_kernel<<<NW_IH0 / 256, 256, 0, stream>>>(eWih0, eWih0h, eWih0l,
                                               3, 1, HID, NW_IH0);
  swz_kernel<<<NW / 256, 256, 0, stream>>>(eWhh0, eWhh0h, eWhh0l,
                                           3, 16, HID, NW);
  swz_kernel<<<NW / 256, 256, 0, stream>>>(eWih1, eWih1h, eWih1l,
                                           3, 16, HID, NW);
  swz_kernel<<<NW / 256, 256, 0, stream>>>(eWhh1, eWhh1h, eWhh1l,
                                           3, 16, HID, NW);
  swz_kernel<<<NW / 256, 256, 0, stream>>>(dWhh, dWhh0h, dWhh0l,
                                           3, 16, HID, NW);
  swz_kernel<<<NW / 256, 256, 0, stream>>>(dWhh + (size_t)NW, dWhh1h, dWhh1l,
                                           3, 16, HID, NW);
  swz_kernel<<<NW / 256, 256, 0, stream>>>(dWih + (size_t)NW, dWih1h, dWih1l,
                                           3, 16, HID, NW);
  swz_kernel<<<NW_FC / 256, 256, 0, stream>>>(fcW, fcWh, fcWl,
                                              1, 16, VOC, NW_FC);
  // one-time x split
  xsplit_kernel<<<(int)(XN / 4 / 256), 256, 0, stream>>>(x, xhi, xlo,
                                                         (int)(XN / 4));

  // decoder layer0 input table (bias folded)
  e0_kernel<<<768, 256, 0, stream>>>(emb, dWih, dbih, E0);

  // ---------------- encoder: 513 pipelined steps ----------------
  for (int s = 0; s <= SEQ; ++s) {
    enc_step_mfma<<<512, 256, 0, stream>>>(
        s, xhi, xlo,
        eWih0h, eWih0l, ebih0, eWhh0h, eWhh0l, ebhh0,
        eWih1h, eWih1l, ebih1, eWhh1h, eWhh1l, ebhh1,
        h0f, h1f, h0hi, h0lo, h1hi, h1lo);
  }

  // decoder initial hidden = encoder finals (slot 1: 511&1 == 1)
  hipMemcpyAsync(hd0f + BH, h0f + BH, BH * 4, hipMemcpyDeviceToDevice, stream);
  hipMemcpyAsync(hd1f + BH, h1f + BH, BH * 4, hipMemcpyDeviceToDevice, stream);
  hipMemcpyAsync(d0hi + BH, h0hi + BH, BH * 2, hipMemcpyDeviceToDevice, stream);
  hipMemcpyAsync(d0lo + BH, h0lo + BH, BH * 2, hipMemcpyDeviceToDevice, stream);
  hipMemcpyAsync(d1hi + BH, h1hi + BH, BH * 2, hipMemcpyDeviceToDevice, stream);
  hipMemcpyAsync(d1lo + BH, h1lo + BH, BH * 2, hipMemcpyDeviceToDevice, stream);

  // ---------------- decoder: 64 greedy AR steps ----------------
  for (int t = 0; t < TT; ++t) {
    const size_t sp = ((t + 1) & 1) * BH, so = (t & 1) * BH;
    gru0_main<<<512, 256, 0, stream>>>(d0hi + sp, d0lo + sp,
                                       dWhh0h, dWhh0l, Pg);
    gru0_epi<<<256, 256, 0, stream>>>(Pg, dbhh, E0, tok, hd0f + sp,
                                      hd0f + so, d0hi + so, d0lo + so);

    dec_l1_main<<<512, 256, 0, stream>>>(d1hi + sp, d1lo + sp,
                                         d0hi + so, d0lo + so,
                                         dWhh1h, dWhh1l, dWih1h, dWih1l,
                                         Phh, Pih);
    dec_l1_epi<<<256, 256, 0, stream>>>(Phh, Pih, dbih + GD, dbhh + GD,
                                        hd1f + sp, hd1f + so,
                                        d1hi + so, d1lo + so);
    fc_main<<<256, 256, 0, stream>>>(d1hi + so, d1lo + so, fcWh, fcWl, Pfc);
    fc_epi<<<256, 256, 0, stream>>>(Pfc, fcb, out, t, tok);
  }

  // h_fin = (L,B,H): final decoder hiddens (slot 1, 63&1 == 1)
  hipMemcpyAsync(out + (size_t)BSZ * TT * VOC, hd0f + BH, BH * 4,
                 hipMemcpyDeviceToDevice, stream);
  hipMemcpyAsync(out + (size_t)BSZ * TT * VOC + BH, hd1f + BH, BH * 4,
                 hipMemcpyDeviceToDevice, stream);
}

// Round 6
// 14928.368 us; speedup vs baseline: 1.5775x; 1.5775x over previous
//
#include <hip/hip_runtime.h>
#include <math.h>

namespace {

constexpr int BSZ = 256;   // batch
constexpr int SEQ = 512;   // encoder seq len
constexpr int KIN = 64;    // encoder input feature dim
constexpr int HID = 1024;  // hidden dim
constexpr int GD  = 3072;  // 3*HID
constexpr int VOC = 512;   // vocab
constexpr int TT  = 64;    // decoder steps

typedef _Float16 half_t;
typedef _Float16 half4 __attribute__((ext_vector_type(4)));
typedef _Float16 half8 __attribute__((ext_vector_type(8)));
typedef float f32x4 __attribute__((ext_vector_type(4)));

constexpr float LOSCL = 4096.f;        // lo-part scale 2^12
constexpr float LOINV = 1.f / 4096.f;

// XCD-aware decode for 256-block tile sets: 8 m-tiles (32 rows) x 32 c-tiles
// (32 cols). All m-tiles of a c-slice share blk&7 -> same XCD.
__device__ __forceinline__ void decode_mc(int bb, int& m0, int& c0) {
  int c_lo = bb & 7, rest = bb >> 3;
  int m = rest & 7, c_hi = rest >> 3;      // m in [0,8), c_hi in [0,4)
  m0 = m * 32;
  c0 = (c_hi * 8 + c_lo) * 32;
}

// ---------------------------------------------------------------------------
// Weight swizzle (one-time): rewrite W [NG*HIDR][NKCH*64] f32 into hi/lo fp16
// arrays in MFMA fragment order (layout identical to R0 — verified):
//   off = ((((ct*NKCH + kc)*4 + w4)*NG + g)*512) + l*8 + j
//   value = W[g*HIDR + ct*32 + (w4&1)*16 + (l&15)]
//            [kc*64 + (w4>>1)*32 + (l>>4)*8 + j]
// ---------------------------------------------------------------------------
__global__ __launch_bounds__(256) void swz_kernel(
    const float* __restrict__ src, half_t* __restrict__ hi,
    half_t* __restrict__ lo, int NG, int NKCH, int HIDR, int n)
{
  int i = blockIdx.x * 256 + threadIdx.x;
  if (i >= n) return;
  int j = i & 7, l = (i >> 3) & 63;
  int frag = i >> 9;
  int g = frag % NG;
  int rest = frag / NG;
  int w4 = rest & 3;
  int rest2 = rest >> 2;
  int kc = rest2 % NKCH;
  int ct = rest2 / NKCH;
  int ldw = NKCH * 64;
  int row = g * HIDR + ct * 32 + (w4 & 1) * 16 + (l & 15);
  int col = kc * 64 + (w4 >> 1) * 32 + (l >> 4) * 8 + j;
  float f = src[(size_t)row * ldw + col];
  half_t h = (half_t)f;
  hi[i] = h;
  lo[i] = (half_t)((f - (float)h) * LOSCL);
}

// x pre-split (one-time): x f32 -> xhi/xlo fp16, same linear (b,s,k) layout.
__global__ __launch_bounds__(256) void xsplit_kernel(
    const float* __restrict__ x, half_t* __restrict__ xhi,
    half_t* __restrict__ xlo, int n4)
{
  int i = blockIdx.x * 256 + threadIdx.x;
  if (i >= n4) return;
  float4 v = ((const float4*)x)[i];
  float vv[4] = {v.x, v.y, v.z, v.w};
  half4 h, lo;
  #pragma unroll
  for (int j = 0; j < 4; ++j) {
    float f = vv[j]; half_t hh = (half_t)f;
    h[j] = hh; lo[j] = (half_t)((f - (float)hh) * LOSCL);
  }
  ((half4*)xhi)[i] = h;
  ((half4*)xlo)[i] = lo;
}

// LDS A tile: [buf][split][row][136]  (+8 pad -> 272B row stride = 68 dwords
// ≡ 4 mod 32). Wide-access bank math (R5 lesson — analyze b128 as 4-dword
// groups, NOT scalar): ds_read_b128 lanes (lr,lk) start at bank
// 4*((lr+lk)%8); each of the 8 start-groups has 8 lanes covering 4 banks ->
// every bank serves exactly 8 dwords = the 256-dword minimum: CONFLICT-FREE.
// ds_write_b128 (arow,aseg): start 4*((arow+2*aseg)%8), same uniform cover.
// 272B also keeps every b128 access 16B-aligned (R5's 268B stride broke
// alignment and scalarized all LDS ops: 15.5 -> 23.5 ms).
typedef half_t AldsT[2][2][32][136];

// ---------------------------------------------------------------------------
// Split-fp16 GEMM core, 128-K chunks, SINGLE barrier per chunk. A is
// PRE-SPLIT in global (hi/lo fp16 row-major, lda in halfs) — staging is a
// pure load->ds_write copy (no conversion VALU in the hot loop).
// Per chunk: [write A(ch)->buf(ch&1)] [barrier] [issue A/B(ch+1) loads]
// [MFMA from buf(ch&1) x B(ch)]. Safe: iter ch+2's writes to buf(ch&1) are
// separated from iter ch's reads by the barrier at iter ch+1.
// Wave map: wv = (colg=wv&1, ksg=wv>>1); wave computes 32 rows x 16 cols x
// its 64-K half of each chunk (sub-ks s2 in {0,1} -> stored fragment
// w4 = colg + 2*s2 at kc = kc0 + 2*ch + ksg). K-partial acc -> combine_ks.
// A/B register-double-buffered; nch must be EVEN.
// ---------------------------------------------------------------------------
template<int NG, int G2>
__device__ __forceinline__ void gemm_swz128(
    const half_t* __restrict__ Ahi, const half_t* __restrict__ Alo,
    size_t lda, int nch,   // K = nch*128
    const half_t* __restrict__ Whi, const half_t* __restrict__ Wlo,
    int ct, int kc0, int nkch_tot, int m0,
    f32x4 (&aH)[4][2], f32x4 (&aL)[4][2], AldsT& Alds)
{
  const int tid = threadIdx.x;
  const int wv = tid >> 6, l = tid & 63, lr = l & 15, lk = l >> 4;
  const int colg = wv & 1, ksg = wv >> 1;
  const int arow = tid >> 3, aseg = tid & 7;
  const half_t* ahp = Ahi + (size_t)(m0 + arow) * lda + aseg * 16;
  const half_t* alp = Alo + (size_t)(m0 + arow) * lda + aseg * 16;

  const size_t FR = (size_t)NG * 512;       // halfs per (kc,w4) frag group
  const size_t S2STR = 2 * FR;              // w4 += 2  (sub-ks step)
  const size_t CSTR = 8 * FR;               // kc += 2  (chunk step)
  const size_t bbase =
      (((size_t)(ct * nkch_tot + kc0 + ksg)) * 4 + colg) * FR + l * 8;
  const half_t* bph = Whi + bbase;
  const half_t* bpl = Wlo + bbase;

  half8 paE[4], paO[4];                     // {hi seg0, hi seg1, lo seg0, lo seg1}
  half8 bhE[2 * NG], blE[2 * NG], bhO[2 * NG], blO[2 * NG];
  paE[0] = *(const half8*)(ahp);
  paE[1] = *(const half8*)(ahp + 8);
  paE[2] = *(const half8*)(alp);
  paE[3] = *(const half8*)(alp + 8);
  #pragma unroll
  for (int s2 = 0; s2 < 2; ++s2)
    #pragma unroll
    for (int g = 0; g < NG; ++g) {
      bhE[s2 * NG + g] = *(const half8*)(bph + s2 * S2STR + g * 512);
      blE[s2 * NG + g] = *(const half8*)(bpl + s2 * S2STR + g * 512);
    }

#define SWC(pac, bhc, blc, pan, bhn, bln, CH, BUF)                            \
  {                                                                           \
    *(half8*)&Alds[BUF][0][arow][aseg * 16] = pac[0];                         \
    *(half8*)&Alds[BUF][0][arow][aseg * 16 + 8] = pac[1];                     \
    *(half8*)&Alds[BUF][1][arow][aseg * 16] = pac[2];                         \
    *(half8*)&Alds[BUF][1][arow][aseg * 16 + 8] = pac[3];                     \
    __syncthreads();                                                          \
    if ((CH) + 1 < nch) {                                                     \
      const size_t aco = (size_t)((CH) + 1) * 128;                            \
      pan[0] = *(const half8*)(ahp + aco);                                    \
      pan[1] = *(const half8*)(ahp + aco + 8);                                \
      pan[2] = *(const half8*)(alp + aco);                                    \
      pan[3] = *(const half8*)(alp + aco + 8);                                \
      _Pragma("unroll") for (int s2 = 0; s2 < 2; ++s2)                        \
        _Pragma("unroll") for (int g = 0; g < NG; ++g) {                      \
          bhn[s2 * NG + g] =                                                  \
              *(const half8*)(bph + ((CH) + 1) * CSTR + s2 * S2STR + g * 512);\
          bln[s2 * NG + g] =                                                  \
              *(const half8*)(bpl + ((CH) + 1) * CSTR + s2 * S2STR + g * 512);\
        }                                                                     \
    }                                                                         \
    _Pragma("unroll") for (int s2 = 0; s2 < 2; ++s2) {                        \
      half8 ah0 = *(const half8*)&Alds[BUF][0][lr][ksg * 64 + s2 * 32 + lk * 8];      \
      half8 ah1 = *(const half8*)&Alds[BUF][0][16 + lr][ksg * 64 + s2 * 32 + lk * 8]; \
      half8 al0 = *(const half8*)&Alds[BUF][1][lr][ksg * 64 + s2 * 32 + lk * 8];      \
      half8 al1 = *(const half8*)&Alds[BUF][1][16 + lr][ksg * 64 + s2 * 32 + lk * 8]; \
      _Pragma("unroll") for (int g = 0; g < NG; ++g) {                        \
        const int slot = (g == 2) ? G2 : g;                                   \
        half8 bh = bhc[s2 * NG + g];                                          \
        half8 bl = blc[s2 * NG + g];                                          \
        aH[slot][0] = __builtin_amdgcn_mfma_f32_16x16x32_f16(ah0, bh, aH[slot][0], 0, 0, 0); \
        aH[slot][1] = __builtin_amdgcn_mfma_f32_16x16x32_f16(ah1, bh, aH[slot][1], 0, 0, 0); \
        aL[slot][0] = __builtin_amdgcn_mfma_f32_16x16x32_f16(ah0, bl, aL[slot][0], 0, 0, 0); \
        aL[slot][0] = __builtin_amdgcn_mfma_f32_16x16x32_f16(al0, bh, aL[slot][0], 0, 0, 0); \
        aL[slot][1] = __builtin_amdgcn_mfma_f32_16x16x32_f16(ah1, bl, aL[slot][1], 0, 0, 0); \
        aL[slot][1] = __builtin_amdgcn_mfma_f32_16x16x32_f16(al1, bh, aL[slot][1], 0, 0, 0); \
      }                                                                       \
    }                                                                         \
  }

  for (int ch = 0; ch < nch; ch += 2) {
    SWC(paE, bhE, blE, paO, bhO, blO, ch, 0)
    SWC(paO, bhO, blO, paE, bhE, blE, (ch + 1), 1)
  }
#undef SWC
}

// K=64 pass (encoder layer0 ih). Single chunk into buf0; wave (colg,ksg)
// takes stored fragment w4 = colg + 2*ksg (its 32-K half).
// A pre-split; staging is pure copy. Safe to write buf0 immediately after an
// even-nch gemm_swz128 pass.
template<int NG, int G2>
__device__ __forceinline__ void gemm_swz64(
    const half_t* __restrict__ Ahi, const half_t* __restrict__ Alo,
    size_t lda,
    const half_t* __restrict__ Whi, const half_t* __restrict__ Wlo,
    int ct, int nkch_tot, int m0,
    f32x4 (&aH)[4][2], f32x4 (&aL)[4][2], AldsT& Alds)
{
  const int tid = threadIdx.x;
  const int wv = tid >> 6, l = tid & 63, lr = l & 15, lk = l >> 4;
  const int colg = wv & 1, ksg = wv >> 1;
  const int arow = tid >> 3, aseg = tid & 7;
  const half_t* ahp = Ahi + (size_t)(m0 + arow) * lda + aseg * 8;
  const half_t* alp = Alo + (size_t)(m0 + arow) * lda + aseg * 8;

  const size_t FR = (size_t)NG * 512;
  const size_t bbase =
      (((size_t)(ct * nkch_tot)) * 4 + (colg + 2 * ksg)) * FR + l * 8;
  half8 bh[NG], bl[NG];
  #pragma unroll
  for (int g = 0; g < NG; ++g) {
    bh[g] = *(const half8*)(Whi + bbase + g * 512);
    bl[g] = *(const half8*)(Wlo + bbase + g * 512);
  }
  half8 hi8 = *(const half8*)(ahp);
  half8 lo8 = *(const half8*)(alp);
  *(half8*)&Alds[0][0][arow][aseg * 8] = hi8;
  *(half8*)&Alds[0][1][arow][aseg * 8] = lo8;
  __syncthreads();
  half8 ah0 = *(const half8*)&Alds[0][0][lr][ksg * 32 + lk * 8];
  half8 ah1 = *(const half8*)&Alds[0][0][16 + lr][ksg * 32 + lk * 8];
  half8 al0 = *(const half8*)&Alds[0][1][lr][ksg * 32 + lk * 8];
  half8 al1 = *(const half8*)&Alds[0][1][16 + lr][ksg * 32 + lk * 8];
  #pragma unroll
  for (int g = 0; g < NG; ++g) {
    const int slot = (g == 2) ? G2 : g;
    aH[slot][0] = __builtin_amdgcn_mfma_f32_16x16x32_f16(ah0, bh[g], aH[slot][0], 0, 0, 0);
    aH[slot][1] = __builtin_amdgcn_mfma_f32_16x16x32_f16(ah1, bh[g], aH[slot][1], 0, 0, 0);
    aL[slot][0] = __builtin_amdgcn_mfma_f32_16x16x32_f16(ah0, bl[g], aL[slot][0], 0, 0, 0);
    aL[slot][0] = __builtin_amdgcn_mfma_f32_16x16x32_f16(al0, bh[g], aL[slot][0], 0, 0, 0);
    aL[slot][1] = __builtin_amdgcn_mfma_f32_16x16x32_f16(ah1, bl[g], aL[slot][1], 0, 0, 0);
    aL[slot][1] = __builtin_amdgcn_mfma_f32_16x16x32_f16(al1, bh[g], aL[slot][1], 0, 0, 0);
  }
}

// Fold lo into hi, then fold ksg=1 partials into ksg=0 waves via LDS
// exchange. Lane stride = NS*8+4 dwords: ≡4 mod 32 -> bank start 4*(l%8),
// 8 uniform groups = conflict-free (the old NS*8 stride was ≡0 mod 32:
// all 64 lanes of a wave on the same 4 banks, ~8x serialization); stride
// stays a multiple of 16B so f32x4 ops remain aligned (R5 lesson).
// xch >= 128*(NS*8+4) floats; A-LDS region reused — the leading
// __syncthreads makes that safe. tid<128 then holds finals. Callers
// touching LDS after this must __syncthreads() first.
template<int NS>
__device__ __forceinline__ void combine_ks(
    f32x4 (&aH)[4][2], f32x4 (&aL)[4][2], float* __restrict__ xch)
{
  const int tid = threadIdx.x;
  const int wv = tid >> 6, l = tid & 63;
  const int colg = wv & 1, ksg = wv >> 1;
  #pragma unroll
  for (int q = 0; q < NS; ++q)
    #pragma unroll
    for (int mf = 0; mf < 2; ++mf)
      aH[q][mf] = aH[q][mf] + aL[q][mf] * LOINV;
  __syncthreads();                        // last gemm LDS reads complete
  float* base = xch + ((size_t)colg * 64 + l) * (NS * 8 + 4);
  if (ksg == 1) {
    #pragma unroll
    for (int q = 0; q < NS; ++q)
      #pragma unroll
      for (int mf = 0; mf < 2; ++mf)
        *(f32x4*)(base + q * 8 + mf * 4) = aH[q][mf];
  }
  __syncthreads();
  if (ksg == 0) {
    #pragma unroll
    for (int q = 0; q < NS; ++q)
      #pragma unroll
      for (int mf = 0; mf < 2; ++mf)
        aH[q][mf] = aH[q][mf] + *(const f32x4*)(base + q * 8 + mf * 4);
  }
}

// GRU epilogue (runs on tid<128 after combine_ks). vv = folded slots.
// Writes f32 h AND pre-split hi/lo fp16 h (consumed as GEMM-A next step).
__device__ __forceinline__ void gru_epi32s(
    f32x4 (&vv)[4][2],
    const float* __restrict__ bih, const float* __restrict__ bhh,
    const float* __restrict__ hprev, float* __restrict__ hout,
    half_t* __restrict__ houthi, half_t* __restrict__ houtlo,
    int m0, int c0)
{
  const int tid = threadIdx.x;
  if (tid >= 128) return;
  const int wv = tid >> 6, l = tid & 63, lr = l & 15, lk = l >> 4;
  const int c = c0 + (wv & 1) * 16 + lr;
  float bhr = bhh[c], bhz = bhh[HID + c], bhn = bhh[2 * HID + c];
  float bir = 0.f, biz = 0.f, bin = 0.f;
  if (bih) { bir = bih[c]; biz = bih[HID + c]; bin = bih[2 * HID + c]; }
  #pragma unroll
  for (int mf = 0; mf < 2; ++mf) {
    #pragma unroll
    for (int i = 0; i < 4; ++i) {
      int b = m0 + mf * 16 + lk * 4 + i;
      float rs = vv[0][mf][i] + bhr + bir;
      float zs = vv[1][mf][i] + bhz + biz;
      float nx = vv[2][mf][i] + bin;
      float nh = vv[3][mf][i] + bhn;
      float r = 1.f / (1.f + expf(-rs));
      float z = 1.f / (1.f + expf(-zs));
      float n = tanhf(nx + r * nh);
      float o = (1.f - z) * n + z * hprev[(size_t)b * HID + c];
      hout[(size_t)b * HID + c] = o;
      half_t hv = (half_t)o;
      houthi[(size_t)b * HID + c] = hv;
      houtlo[(size_t)b * HID + c] = (half_t)((o - (float)hv) * LOSCL);
    }
  }
}

// Write 3 gate slots (0,1,s2) as f32 partials P[3][BSZ][HID]. tid<128.
__device__ __forceinline__ void write_partials32(
    f32x4 (&vv)[4][2], int s2, float* __restrict__ P, int m0, int c0)
{
  const int tid = threadIdx.x;
  if (tid >= 128) return;
  const int wv = tid >> 6, l = tid & 63, lr = l & 15, lk = l >> 4;
  const int c = c0 + (wv & 1) * 16 + lr;
  #pragma unroll
  for (int g = 0; g < 3; ++g) {
    const int slot = (g == 2) ? s2 : g;
    #pragma unroll
    for (int mf = 0; mf < 2; ++mf) {
      #pragma unroll
      for (int i = 0; i < 4; ++i) {
        int b = m0 + mf * 16 + lk * 4 + i;
        P[((size_t)g * BSZ + b) * HID + c] = vv[slot][mf][i];
      }
    }
  }
}

#define INIT_ACC(aH, aL)                                  \
  _Pragma("unroll") for (int q = 0; q < 4; ++q)           \
    _Pragma("unroll") for (int m_ = 0; m_ < 2; ++m_) {    \
      aH[q][m_] = (f32x4){0.f, 0.f, 0.f, 0.f};            \
      aL[q][m_] = (f32x4){0.f, 0.f, 0.f, 0.f};            \
    }

// ---------------------------------------------------------------------------
// Encoder step: blocks [0,256) layer0 @ s; [256,512) layer1 @ s-1 (pipelined).
// Ring: layer writes slot (s&1), reads slot ((s+1)&1). 2 blocks/CU.
// ---------------------------------------------------------------------------
__global__ __launch_bounds__(256, 2) void enc_step_mfma(
    int s, const half_t* __restrict__ xhi, const half_t* __restrict__ xlo,
    const half_t* __restrict__ Wih0h, const half_t* __restrict__ Wih0l,
    const float* __restrict__ bih0,
    const half_t* __restrict__ Whh0h, const half_t* __restrict__ Whh0l,
    const float* __restrict__ bhh0,
    const half_t* __restrict__ Wih1h, const half_t* __restrict__ Wih1l,
    const float* __restrict__ bih1,
    const half_t* __restrict__ Whh1h, const half_t* __restrict__ Whh1l,
    const float* __restrict__ bhh1,
    float* __restrict__ h0f, float* __restrict__ h1f,
    half_t* __restrict__ h0hi, half_t* __restrict__ h0lo,
    half_t* __restrict__ h1hi, half_t* __restrict__ h1lo)
{
  __shared__ __align__(16) AldsT Alds;
  f32x4 aH[4][2], aL[4][2];
  INIT_ACC(aH, aL)
  const size_t BH = (size_t)BSZ * HID;
  int blk = blockIdx.x;
  if (blk < 256) {
    if (s >= SEQ) return;
    int m0, c0; decode_mc(blk, m0, c0);
    int ct = c0 >> 5;
    const size_t sp = ((s + 1) & 1) * BH, so = (s & 1) * BH;
    gemm_swz128<3, 3>(h0hi + sp, h0lo + sp, HID, 8, Whh0h, Whh0l,
                      ct, 0, 16, m0, aH, aL, Alds);
    gemm_swz64<3, 2>(xhi + (size_t)s * KIN, xlo + (size_t)s * KIN,
                     (size_t)SEQ * KIN, Wih0h, Wih0l, ct, 1, m0, aH, aL, Alds);
    combine_ks<4>(aH, aL, (float*)Alds);
    gru_epi32s(aH, bih0, bhh0, h0f + sp, h0f + so, h0hi + so, h0lo + so,
               m0, c0);
  } else {
    if (s < 1) return;
    int u = s - 1;
    int m0, c0; decode_mc(blk - 256, m0, c0);
    int ct = c0 >> 5;
    const size_t up = ((u + 1) & 1) * BH, uo = (u & 1) * BH;
    gemm_swz128<3, 3>(h1hi + up, h1lo + up, HID, 8, Whh1h, Whh1l,
                      ct, 0, 16, m0, aH, aL, Alds);
    gemm_swz128<3, 2>(h0hi + uo, h0lo + uo, HID, 8, Wih1h, Wih1l,
                      ct, 0, 16, m0, aH, aL, Alds);
    combine_ks<4>(aH, aL, (float*)Alds);
    gru_epi32s(aH, bih1, bhh1, h1f + up, h1f + uo, h1hi + uo, h1lo + uo,
               m0, c0);
  }
}

// Decoder layer0 main: hh GEMM, K-split x2 -> 512 blocks (2/CU TLP).
// Pg layout: [kh][3][BSZ][HID].
__global__ __launch_bounds__(256, 2) void gru0_main(
    const half_t* __restrict__ hphi, const half_t* __restrict__ hplo,
    const half_t* __restrict__ Whhh, const half_t* __restrict__ Whhl,
    float* __restrict__ Pg)
{
  __shared__ __align__(16) AldsT Alds;
  f32x4 aH[4][2], aL[4][2];
  INIT_ACC(aH, aL)
  int bb = blockIdx.x;
  int kh = bb >> 8;
  int m0, c0; decode_mc(bb & 255, m0, c0);
  int ct = c0 >> 5;
  gemm_swz128<3, 3>(hphi + kh * 512, hplo + kh * 512, HID, 4, Whhh, Whhl,
                    ct, kh * 8, 16, m0, aH, aL, Alds);
  combine_ks<4>(aH, aL, (float*)Alds);
  write_partials32(aH, 3, Pg + (size_t)kh * 3 * BSZ * HID, m0, c0);
}

// Decoder layer0 epilogue: combine K-halves + E-gather (token from tok[]) +
// GRU cell. bih0 folded into E. Also writes pre-split hi/lo h.
__global__ __launch_bounds__(256) void gru0_epi(
    const float* __restrict__ Pg, const float* __restrict__ bhh,
    const float* __restrict__ E, const int* __restrict__ tok,
    const float* __restrict__ hprev, float* __restrict__ hout,
    half_t* __restrict__ houthi, half_t* __restrict__ houtlo)
{
  int idx = (blockIdx.x * 256 + threadIdx.x) * 4;
  int b = idx >> 10, c = idx & 1023;
  const size_t BH3 = (size_t)3 * BSZ * HID;
  float4 r0 = *(const float4*)&Pg[((size_t)0 * BSZ + b) * HID + c];
  float4 z0 = *(const float4*)&Pg[((size_t)1 * BSZ + b) * HID + c];
  float4 n0 = *(const float4*)&Pg[((size_t)2 * BSZ + b) * HID + c];
  float4 r1 = *(const float4*)&Pg[BH3 + ((size_t)0 * BSZ + b) * HID + c];
  float4 z1 = *(const float4*)&Pg[BH3 + ((size_t)1 * BSZ + b) * HID + c];
  float4 n1 = *(const float4*)&Pg[BH3 + ((size_t)2 * BSZ + b) * HID + c];
  const float* Er = E + (size_t)tok[b] * GD;
  float4 exr = *(const float4*)&Er[c];
  float4 exz = *(const float4*)&Er[HID + c];
  float4 exn = *(const float4*)&Er[2 * HID + c];
  float4 hp = *(const float4*)&hprev[(size_t)b * HID + c];
  float r0v[4] = {r0.x, r0.y, r0.z, r0.w}, z0v[4] = {z0.x, z0.y, z0.z, z0.w};
  float n0v[4] = {n0.x, n0.y, n0.z, n0.w}, r1v[4] = {r1.x, r1.y, r1.z, r1.w};
  float z1v[4] = {z1.x, z1.y, z1.z, z1.w}, n1v[4] = {n1.x, n1.y, n1.z, n1.w};
  float exrv[4] = {exr.x, exr.y, exr.z, exr.w};
  float exzv[4] = {exz.x, exz.y, exz.z, exz.w};
  float exnv[4] = {exn.x, exn.y, exn.z, exn.w};
  float hpv[4] = {hp.x, hp.y, hp.z, hp.w};
  float ov[4];
  half4 hh, hl;
  #pragma unroll
  for (int j = 0; j < 4; ++j) {
    int cc = c + j;
    float rs = r0v[j] + r1v[j] + bhh[cc] + exrv[j];
    float zs = z0v[j] + z1v[j] + bhh[HID + cc] + exzv[j];
    float nh = n0v[j] + n1v[j] + bhh[2 * HID + cc];
    float r = 1.f / (1.f + expf(-rs));
    float z = 1.f / (1.f + expf(-zs));
    float n = tanhf(exnv[j] + r * nh);
    ov[j] = (1.f - z) * n + z * hpv[j];
    half_t hv = (half_t)ov[j];
    hh[j] = hv;
    hl[j] = (half_t)((ov[j] - (float)hv) * LOSCL);
  }
  float4 o; o.x = ov[0]; o.y = ov[1]; o.z = ov[2]; o.w = ov[3];
  *(float4*)&hout[(size_t)b * HID + c] = o;
  *(half4*)&houthi[(size_t)b * HID + c] = hh;
  *(half4*)&houtlo[(size_t)b * HID + c] = hl;
}

// Decoder layer1: hh and ih passes as parallel blocks writing partials.
// grid 512: [0,256) hh (A = hd1prev splits), [256,512) ih (A = ho0 splits).
__global__ __launch_bounds__(256, 2) void dec_l1_main(
    const half_t* __restrict__ hd1hi, const half_t* __restrict__ hd1lo,
    const half_t* __restrict__ ho0hi, const half_t* __restrict__ ho0lo,
    const half_t* __restrict__ Whhh, const half_t* __restrict__ Whhl,
    const half_t* __restrict__ Wihh, const half_t* __restrict__ Wihl,
    float* __restrict__ Phh, float* __restrict__ Pih)
{
  __shared__ __align__(16) AldsT Alds;
  f32x4 aH[4][2], aL[4][2];
  INIT_ACC(aH, aL)
  int bb = blockIdx.x;
  if (bb < 256) {
    int m0, c0; decode_mc(bb, m0, c0);
    gemm_swz128<3, 3>(hd1hi, hd1lo, HID, 8, Whhh, Whhl, c0 >> 5, 0, 16, m0,
                      aH, aL, Alds);
    combine_ks<4>(aH, aL, (float*)Alds);
    write_partials32(aH, 3, Phh, m0, c0);
  } else {
    int m0, c0; decode_mc(bb - 256, m0, c0);
    gemm_swz128<3, 2>(ho0hi, ho0lo, HID, 8, Wihh, Wihl, c0 >> 5, 0, 16, m0,
                      aH, aL, Alds);
    combine_ks<4>(aH, aL, (float*)Alds);
    write_partials32(aH, 2, Pih, m0, c0);
  }
}

// Decoder layer1 epilogue: combine partials -> GRU cell (+ split h out).
__global__ __launch_bounds__(256) void dec_l1_epi(
    const float* __restrict__ Phh, const float* __restrict__ Pih,
    const float* __restrict__ bih, const float* __restrict__ bhh,
    const float* __restrict__ hprev, float* __restrict__ hout,
    half_t* __restrict__ houthi, half_t* __restrict__ houtlo)
{
  int idx = (blockIdx.x * 256 + threadIdx.x) * 4;
  int b = idx >> 10, c = idx & 1023;
  float4 rh = *(const float4*)&Phh[((size_t)0 * BSZ + b) * HID + c];
  float4 zh = *(const float4*)&Phh[((size_t)1 * BSZ + b) * HID + c];
  float4 nh = *(const float4*)&Phh[((size_t)2 * BSZ + b) * HID + c];
  float4 rx = *(const float4*)&Pih[((size_t)0 * BSZ + b) * HID + c];
  float4 zx = *(const float4*)&Pih[((size_t)1 * BSZ + b) * HID + c];
  float4 nx = *(const float4*)&Pih[((size_t)2 * BSZ + b) * HID + c];
  float4 hp = *(const float4*)&hprev[(size_t)b * HID + c];
  float rhv[4] = {rh.x, rh.y, rh.z, rh.w}, zhv[4] = {zh.x, zh.y, zh.z, zh.w};
  float nhv[4] = {nh.x, nh.y, nh.z, nh.w}, rxv[4] = {rx.x, rx.y, rx.z, rx.w};
  float zxv[4] = {zx.x, zx.y, zx.z, zx.w}, nxv[4] = {nx.x, nx.y, nx.z, nx.w};
  float hpv[4] = {hp.x, hp.y, hp.z, hp.w};
  float ov[4];
  half4 hh, hl;
  #pragma unroll
  for (int j = 0; j < 4; ++j) {
    int cc = c + j;
    float r = 1.f / (1.f + expf(-(rhv[j] + rxv[j] + bhh[cc] + bih[cc])));
    float z = 1.f / (1.f + expf(-(zhv[j] + zxv[j] + bhh[HID + cc] + bih[HID + cc])));
    float n = tanhf(nxv[j] + bih[2 * HID + cc] + r * (nhv[j] + bhh[2 * HID + cc]));
    ov[j] = (1.f - z) * n + z * hpv[j];
    half_t hv = (half_t)ov[j];
    hh[j] = hv;
    hl[j] = (half_t)((ov[j] - (float)hv) * LOSCL);
  }
  float4 o; o.x = ov[0]; o.y = ov[1]; o.z = ov[2]; o.w = ov[3];
  *(float4*)&hout[(size_t)b * HID + c] = o;
  *(half4*)&houthi[(size_t)b * HID + c] = hh;
  *(half4*)&houtlo[(size_t)b * HID + c] = hl;
}

// FC main: K-split x4 partial logits (no bias). grid 512 = 4kh x 8m x 16v
// (2 blocks/CU — was 256 = 1/CU). Each kh covers K=256 (2 chunks, even).
// Pfc layout: [kh][BSZ][VOC]. A = ho1 splits.
__global__ __launch_bounds__(256, 2) void fc_main(
    const half_t* __restrict__ hhi, const half_t* __restrict__ hlo,
    const half_t* __restrict__ Wh, const half_t* __restrict__ Wl,
    float* __restrict__ Pfc)
{
  __shared__ __align__(16) AldsT Alds;
  f32x4 aH[4][2], aL[4][2];
  INIT_ACC(aH, aL)
  int bb = blockIdx.x;
  int kh = bb >> 7, sub = bb & 127;
  int v_lo = sub & 7, rest = sub >> 3;
  int m = rest & 7, v_hi = rest >> 3;      // m in [0,8), v_hi in [0,2)
  int m0 = m * 32, v0 = (v_hi * 8 + v_lo) * 32;
  gemm_swz128<1, 0>(hhi + kh * 256, hlo + kh * 256, HID, 2, Wh, Wl,
                    v0 >> 5, kh * 4, 16, m0, aH, aL, Alds);
  combine_ks<1>(aH, aL, (float*)Alds);

  const int tid = threadIdx.x;
  if (tid >= 128) return;
  const int wv = tid >> 6, l = tid & 63, lr = l & 15, lk = l >> 4;
  int v = v0 + (wv & 1) * 16 + lr;
  float* P = Pfc + (size_t)kh * BSZ * VOC;
  #pragma unroll
  for (int mf = 0; mf < 2; ++mf) {
    #pragma unroll
    for (int i = 0; i < 4; ++i) {
      int b = m0 + mf * 16 + lk * 4 + i;
      P[(size_t)b * VOC + v] = aH[0][mf][i];
    }
  }
}

// FC epilogue: sum 4 partials + bias, write logits, row-argmax -> tok.
// grid 256 (one row per block). First-max tie-break == jnp.argmax.
__global__ __launch_bounds__(256) void fc_epi(
    const float* __restrict__ Pfc, const float* __restrict__ fcb,
    float* __restrict__ out, int t, int* __restrict__ tok)
{
  __shared__ float sv[4];
  __shared__ int si[4];
  int b = blockIdx.x, tid = threadIdx.x;
  const size_t PS = (size_t)BSZ * VOC;
  int va = tid, vb = tid + 256;
  float lga = fcb[va], lgb = fcb[vb];
  #pragma unroll
  for (int kh = 0; kh < 4; ++kh) {
    lga += Pfc[kh * PS + (size_t)b * VOC + va];
    lgb += Pfc[kh * PS + (size_t)b * VOC + vb];
  }
  out[((size_t)b * TT + t) * VOC + va] = lga;
  out[((size_t)b * TT + t) * VOC + vb] = lgb;
  float best = lga; int bi = va;
  if (lgb > best) { best = lgb; bi = vb; }   // va < vb: tie keeps va
  #pragma unroll
  for (int off = 1; off < 64; off <<= 1) {
    float ov = __shfl_xor(best, off);
    int oi = __shfl_xor(bi, off);
    if (ov > best || (ov == best && oi < bi)) { best = ov; bi = oi; }
  }
  int wv = tid >> 6;
  if ((tid & 63) == 0) { sv[wv] = best; si[wv] = bi; }
  __syncthreads();
  if (tid == 0) {
    #pragma unroll
    for (int w = 1; w < 4; ++w)
      if (sv[w] > best || (sv[w] == best && si[w] < bi)) { best = sv[w]; bi = si[w]; }
    tok[b] = bi;
  }
}

// E0[v][g] = emb[v] @ dec_Wih0[g] + dec_bih0[g]  (f32 VALU, one-time)
__global__ __launch_bounds__(256) void e0_kernel(
    const float* __restrict__ emb, const float* __restrict__ Wih,
    const float* __restrict__ bih, float* __restrict__ E0)
{
  __shared__ float As[32][34];
  __shared__ float Bs[32][68];
  int m0 = (blockIdx.x & 15) << 5;
  int c0 = (blockIdx.x >> 4) << 6;
  int tid = threadIdx.x, tx = tid & 15, ty = tid >> 4;
  float acc[2][4] = {};
  for (int k0 = 0; k0 < HID; k0 += 32) {
    { int m = tid >> 3, kq = (tid & 7) << 2;
      float4 v = *(const float4*)(emb + (size_t)(m0 + m) * HID + k0 + kq);
      As[kq+0][m] = v.x; As[kq+1][m] = v.y; As[kq+2][m] = v.z; As[kq+3][m] = v.w; }
    #pragma unroll
    for (int r = 0; r < 2; ++r) {
      int idx = (r << 8) + tid;
      int n = idx >> 3, kq = (idx & 7) << 2;
      float4 v = *(const float4*)(Wih + (size_t)(c0 + n) * HID + k0 + kq);
      Bs[kq+0][n] = v.x; Bs[kq+1][n] = v.y; Bs[kq+2][n] = v.z; Bs[kq+3][n] = v.w;
    }
    __syncthreads();
    #pragma unroll 4
    for (int k = 0; k < 32; ++k) {
      float a0 = As[k][(ty << 1)], a1 = As[k][(ty << 1) + 1];
      float4 b = *(const float4*)&Bs[k][tx << 2];
      float bb[4] = {b.x, b.y, b.z, b.w};
      #pragma unroll
      for (int j = 0; j < 4; ++j) {
        acc[0][j] = fmaf(a0, bb[j], acc[0][j]);
        acc[1][j] = fmaf(a1, bb[j], acc[1][j]);
      }
    }
    __syncthreads();
  }
  #pragma unroll
  for (int i = 0; i < 2; ++i) {
    int v = m0 + (ty << 1) + i;
    #pragma unroll
    for (int j = 0; j < 4; ++j) {
      int g = c0 + (tx << 2) + j;
      E0[(size_t)v * GD + g] = acc[i][j] + bih[g];
    }
  }
}

} // anonymous namespace

extern "C" void kernel_launch(void* const* d_in, const int* in_sizes, int n_in,
                              void* d_out, int out_size, void* d_ws, size_t ws_size,
                              hipStream_t stream)
{
  const float* x     = (const float*)d_in[0];
  const float* emb   = (const float*)d_in[1];
  const float* eWih0 = (const float*)d_in[2];
  const float* eWhh0 = (const float*)d_in[3];
  const float* ebih0 = (const float*)d_in[4];
  const float* ebhh0 = (const float*)d_in[5];
  const float* eWih1 = (const float*)d_in[6];
  const float* eWhh1 = (const float*)d_in[7];
  const float* ebih1 = (const float*)d_in[8];
  const float* ebhh1 = (const float*)d_in[9];
  const float* dWih  = (const float*)d_in[10];
  const float* dWhh  = (const float*)d_in[11];
  const float* dbih  = (const float*)d_in[12];
  const float* dbhh  = (const float*)d_in[13];
  const float* fcW   = (const float*)d_in[14];
  const float* fcb   = (const float*)d_in[15];
  float* out = (float*)d_out;

  const size_t BH = (size_t)BSZ * HID;
  const size_t XN = (size_t)BSZ * SEQ * KIN;

  // ---- ws bump allocator ----
  char* p = (char*)d_ws;
  auto alloc = [&](size_t bytes) {
    char* r = p; p += (bytes + 255) & ~(size_t)255; return r;
  };
  float* E0   = (float*)alloc((size_t)VOC * GD * 4);
  float* h0f  = (float*)alloc(2 * BH * 4);
  float* h1f  = (float*)alloc(2 * BH * 4);
  float* hd0f = (float*)alloc(2 * BH * 4);
  float* hd1f = (float*)alloc(2 * BH * 4);
  float* Phh  = (float*)alloc(3 * BH * 4);
  float* Pih  = (float*)alloc(3 * BH * 4);
  float* Pg   = (float*)alloc(6 * BH * 4);           // gru0 K-split partials
  float* Pfc  = (float*)alloc((size_t)4 * BSZ * VOC * 4);
  const int NW_IH0 = GD * KIN, NW = GD * HID, NW_FC = VOC * HID;
  half_t* eWih0h = (half_t*)alloc((size_t)NW_IH0 * 2);
  half_t* eWih0l = (half_t*)alloc((size_t)NW_IH0 * 2);
  half_t* eWhh0h = (half_t*)alloc((size_t)NW * 2);
  half_t* eWhh0l = (half_t*)alloc((size_t)NW * 2);
  half_t* eWih1h = (half_t*)alloc((size_t)NW * 2);
  half_t* eWih1l = (half_t*)alloc((size_t)NW * 2);
  half_t* eWhh1h = (half_t*)alloc((size_t)NW * 2);
  half_t* eWhh1l = (half_t*)alloc((size_t)NW * 2);
  half_t* dWhh0h = (half_t*)alloc((size_t)NW * 2);
  half_t* dWhh0l = (half_t*)alloc((size_t)NW * 2);
  half_t* dWhh1h = (half_t*)alloc((size_t)NW * 2);
  half_t* dWhh1l = (half_t*)alloc((size_t)NW * 2);
  half_t* dWih1h = (half_t*)alloc((size_t)NW * 2);
  half_t* dWih1l = (half_t*)alloc((size_t)NW * 2);
  half_t* fcWh   = (half_t*)alloc((size_t)NW_FC * 2);
  half_t* fcWl   = (half_t*)alloc((size_t)NW_FC * 2);
  // pre-split A arrays (hi/lo fp16): x one-time, h rings per-step
  half_t* xhi  = (half_t*)alloc(XN * 2);
  half_t* xlo  = (half_t*)alloc(XN * 2);
  half_t* h0hi = (half_t*)alloc(2 * BH * 2);
  half_t* h0lo = (half_t*)alloc(2 * BH * 2);
  half_t* h1hi = (half_t*)alloc(2 * BH * 2);
  half_t* h1lo = (half_t*)alloc(2 * BH * 2);
  half_t* d0hi = (half_t*)alloc(2 * BH * 2);
  half_t* d0lo = (half_t*)alloc(2 * BH * 2);
  half_t* d1hi = (half_t*)alloc(2 * BH * 2);
  half_t* d1lo = (half_t*)alloc(2 * BH * 2);
  int* tok = (int*)alloc(BSZ * 4);

  // ---- per-call init ----
  hipMemsetAsync(h0f + BH, 0, BH * 4, stream);   // h0[-1] = 0
  hipMemsetAsync(h1f + BH, 0, BH * 4, stream);   // h1[-1] = 0
  hipMemsetAsync(h0hi + BH, 0, BH * 2, stream);
  hipMemsetAsync(h0lo + BH, 0, BH * 2, stream);
  hipMemsetAsync(h1hi + BH, 0, BH * 2, stream);
  hipMemsetAsync(h1lo + BH, 0, BH * 2, stream);
  hipMemsetAsync(tok, 0, BSZ * 4, stream);       // start token 0

  // ---- one-time weight swizzles (hi/lo fp16, MFMA fragment order) ----
  swz_kernel<<<NW_IH0 / 256, 256, 0, stream>>>(eWih0, eWih0h, eWih0l,
                                               3, 1, HID, NW_IH0);
  swz_kernel<<<NW / 256, 256, 0, stream>>>(eWhh0, eWhh0h, eWhh0l,
                                           3, 16, HID, NW);
  swz_kernel<<<NW / 256, 256, 0, stream>>>(eWih1, eWih1h, eWih1l,
                                           3, 16, HID, NW);
  swz_kernel<<<NW / 256, 256, 0, stream>>>(eWhh1, eWhh1h, eWhh1l,
                                           3, 16, HID, NW);
  swz_kernel<<<NW / 256, 256, 0, stream>>>(dWhh, dWhh0h, dWhh0l,
                                           3, 16, HID, NW);
  swz_kernel<<<NW / 256, 256, 0, stream>>>(dWhh + (size_t)NW, dWhh1h, dWhh1l,
                                           3, 16, HID, NW);
  swz_kernel<<<NW / 256, 256, 0, stream>>>(dWih + (size_t)NW, dWih1h, dWih1l,
                                           3, 16, HID, NW);
  swz_kernel<<<NW_FC / 256, 256, 0, stream>>>(fcW, fcWh, fcWl,
                                              1, 16, VOC, NW_FC);
  // one-time x split
  xsplit_kernel<<<(int)(XN / 4 / 256), 256, 0, stream>>>(x, xhi, xlo,
                                                         (int)(XN / 4));

  // decoder layer0 input table (bias folded)
  e0_kernel<<<768, 256, 0, stream>>>(emb, dWih, dbih, E0);

  // ---------------- encoder: 513 pipelined steps ----------------
  for (int s = 0; s <= SEQ; ++s) {
    enc_step_mfma<<<512, 256, 0, stream>>>(
        s, xhi, xlo,
        eWih0h, eWih0l, ebih0, eWhh0h, eWhh0l, ebhh0,
        eWih1h, eWih1l, ebih1, eWhh1h, eWhh1l, ebhh1,
        h0f, h1f, h0hi, h0lo, h1hi, h1lo);
  }

  // decoder initial hidden = encoder finals (slot 1: 511&1 == 1)
  hipMemcpyAsync(hd0f + BH, h0f + BH, BH * 4, hipMemcpyDeviceToDevice, stream);
  hipMemcpyAsync(hd1f + BH, h1f + BH, BH * 4, hipMemcpyDeviceToDevice, stream);
  hipMemcpyAsync(d0hi + BH, h0hi + BH, BH * 2, hipMemcpyDeviceToDevice, stream);
  hipMemcpyAsync(d0lo + BH, h0lo + BH, BH * 2, hipMemcpyDeviceToDevice, stream);
  hipMemcpyAsync(d1hi + BH, h1hi + BH, BH * 2, hipMemcpyDeviceToDevice, stream);
  hipMemcpyAsync(d1lo + BH, h1lo + BH, BH * 2, hipMemcpyDeviceToDevice, stream);

  // ---------------- decoder: 64 greedy AR steps ----------------
  for (int t = 0; t < TT; ++t) {
    const size_t sp = ((t + 1) & 1) * BH, so = (t & 1) * BH;
    gru0_main<<<512, 256, 0, stream>>>(d0hi + sp, d0lo + sp,
                                       dWhh0h, dWhh0l, Pg);
    gru0_epi<<<256, 256, 0, stream>>>(Pg, dbhh, E0, tok, hd0f + sp,
                                      hd0f + so, d0hi + so, d0lo + so);

    dec_l1_main<<<512, 256, 0, stream>>>(d1hi + sp, d1lo + sp,
                                         d0hi + so, d0lo + so,
                                         dWhh1h, dWhh1l, dWih1h, dWih1l,
                                         Phh, Pih);
    dec_l1_epi<<<256, 256, 0, stream>>>(Phh, Pih, dbih + GD, dbhh + GD,
                                        hd1f + sp, hd1f + so,
                                        d1hi + so, d1lo + so);
    fc_main<<<512, 256, 0, stream>>>(d1hi + so, d1lo + so, fcWh, fcWl, Pfc);
    fc_epi<<<256, 256, 0, stream>>>(Pfc, fcb, out, t, tok);
  }

  // h_fin = (L,B,H): final decoder hiddens (slot 1, 63&1 == 1)
  hipMemcpyAsync(out + (size_t)BSZ * TT * VOC, hd0f + BH, BH * 4,
                 hipMemcpyDeviceToDevice, stream);
  hipMemcpyAsync(out + (size_t)BSZ * TT * VOC + BH, hd1f + BH, BH * 4,
                 hipMemcpyDeviceToDevice, stream);
}